// Round 5
// baseline (474.892 us; speedup 1.0000x reference)
//
#include <hip/hip_runtime.h>

// B=128, C_IN=128, C_HID=256, C_OUT=128, H*W=1600, E=8, TOP_K=2.
#define CIN   128
#define CHID  256
#define COUT  128
#define HWPX  1600

typedef __attribute__((ext_vector_type(8))) short bf16x8;  // 8 bf16 = 4 VGPRs
typedef __attribute__((ext_vector_type(4))) float f32x4;   // MFMA C/D

__device__ __forceinline__ unsigned short f2bf(float f) {
  unsigned int u = __builtin_bit_cast(unsigned int, f);
  u += 0x7FFFu + ((u >> 16) & 1u);
  return (unsigned short)(u >> 16);
}
__device__ __forceinline__ unsigned int pack_bf2(float a, float b) {
  return (unsigned int)f2bf(a) | ((unsigned int)f2bf(b) << 16);
}
// Fast SiLU: v_exp_f32 + v_rcp_f32 (~1e-7 rel err, invisible under bf16).
__device__ __forceinline__ unsigned int silu_gate_pk(float a, float b, float g) {
  const float ea = __builtin_amdgcn_exp2f(a * -1.442695041f);
  const float eb = __builtin_amdgcn_exp2f(b * -1.442695041f);
  const float sa = g * a * __builtin_amdgcn_rcpf(1.0f + ea);
  const float sb = g * b * __builtin_amdgcn_rcpf(1.0f + eb);
  return pack_bf2(sa, sb);
}

// fp32->bf16 convert into PER-INSTRUCTION-ORDER fragment layout (verified r2):
// W1c: ((e*8+grp)*8 + ks*2 + half)*64 + lane; row ch = grp*32 +
//      ((r16>>2)<<3)+(r16&3)+(half<<2) (h-trick permuted), cin chunk = ks*4+q.
// W2c: ((e*8+grp)*8 + mt)*64 + lane; row co = mt*16+r16, ch = grp*32+q*8+j.
__global__ __launch_bounds__(256) void convert_w_kernel(
    const float* __restrict__ W1, const float* __restrict__ W2,
    unsigned short* __restrict__ W1c, unsigned short* __restrict__ W2c) {
  const int i    = blockIdx.x * 256 + threadIdx.x;   // 0 .. 262143
  const int j    = i & 7;
  const int lane = (i >> 3) & 63;
  const int r16  = lane & 15;
  const int q    = lane >> 4;
  {
    const int half = (i >> 9) & 1;
    const int ks   = (i >> 10) & 3;
    const int grp  = (i >> 12) & 7;
    const int e    = i >> 15;
    const int ch   = grp * 32 + ((r16 >> 2) << 3) + (r16 & 3) + (half << 2);
    const int c    = ks * 4 + q;
    W1c[i] = f2bf(W1[(e * CHID + ch) * CIN + c * 8 + j]);
  }
  {
    const int mt  = (i >> 9) & 7;
    const int grp = (i >> 12) & 7;
    const int e   = i >> 15;
    const int co  = mt * 16 + r16;
    W2c[i] = f2bf(W2[(e * COUT + co) * CHID + grp * 32 + q * 8 + j]);
  }
}

// ---------------------------------------------------------------------------
// moe v4 = verified v2 structure + register software-pipeline of weight
// slices: W1(gs+1) and W2(gs) are issued at the top of each gs body and
// consumed one phase later, so L2/L3 load latency hides under MFMA+SiLU.
// Single pass over x (fp32, coalesced), 64-px tiles, full-line 256 B stores.
// ---------------------------------------------------------------------------
__global__ __launch_bounds__(256, 2) void moe_kernel(
    const float* __restrict__ x, const float* __restrict__ wts,
    const int* __restrict__ idx, const unsigned short* __restrict__ W1,
    const float* __restrict__ b1, const unsigned short* __restrict__ W2,
    const float* __restrict__ b2, float* __restrict__ out) {
  // LDS: x tiles only, 4 waves x 16 KB. 64 KB -> 2 blocks/CU.
  __shared__ __align__(16) unsigned short lds[32768];

  const int tid  = threadIdx.x;
  const int wave = tid >> 6;
  const int lane = tid & 63;
  const int q    = lane >> 4;
  const int r16  = lane & 15;

  const int  b    = blockIdx.x / 7;
  const int  t4   = blockIdx.x % 7;
  const int  tile = t4 * 4 + wave;           // 0..27 (25..27 idle)
  if (tile >= 25) return;                    // no barriers anywhere -> safe
  const int  px0  = tile * 64;

  unsigned short* xw = &lds[wave * 8192];    // this wave's 16 KB x region
  const int lane8 = lane * 8;

  const int   e0 = __builtin_amdgcn_readfirstlane(idx[b * 2 + 0]);
  const int   e1 = __builtin_amdgcn_readfirstlane(idx[b * 2 + 1]);
  const float g0 = wts[b * 2 + 0], g1 = wts[b * 2 + 1];

  // ---- prefetch W1 slice gs=0 into registers (lands under x staging)
  bf16x8 n1[8];
  {
    const unsigned short* w1s0 = W1 + ((long)(e0 * 8 + 0) << 12);
#pragma unroll
    for (int k = 0; k < 8; ++k)
      n1[k] = *reinterpret_cast<const bf16x8*>(&w1s0[k * 512 + lane8]);
  }

  // ---- stage x tile (within-wave producer/consumer -> no barrier needed)
  {
    const float* xb = x + (long)b * CIN * HWPX + px0 + lane;
#pragma unroll 4
    for (int c = 0; c < 16; ++c) {
      float v[8];
#pragma unroll
      for (int jj = 0; jj < 8; ++jj) v[jj] = xb[(long)(c * 8 + jj) * HWPX];
      union { bf16x8 w; unsigned int u[4]; } t;
#pragma unroll
      for (int d = 0; d < 4; ++d) t.u[d] = pack_bf2(v[2 * d], v[2 * d + 1]);
      const int slot = (c + lane) & 15;      // rotation swizzle (bank spread)
      *reinterpret_cast<bf16x8*>(&xw[(lane * 16 + slot) * 8]) = t.w;
    }
  }

  f32x4 accO[8][4];
#pragma unroll
  for (int mt = 0; mt < 8; ++mt)
#pragma unroll
    for (int nt = 0; nt < 4; ++nt) accO[mt][nt] = (f32x4){0.f, 0.f, 0.f, 0.f};

#pragma unroll 2
  for (int gs = 0; gs < 16; ++gs) {
    const int   sl  = gs >> 3;
    const int   grp = gs & 7;
    const int   e   = sl ? e1 : e0;
    const float g   = sl ? g1 : g0;
    const unsigned short* w2s = W2 + ((long)(e * 8 + grp) << 12);

    // consume prefetched W1 for this slice
    bf16x8 w1c[8];
#pragma unroll
    for (int k = 0; k < 8; ++k) w1c[k] = n1[k];

    // issue W2 loads for THIS slice (used after GEMM1+SiLU ~1000+ cy later)
    bf16x8 w2c[8];
#pragma unroll
    for (int k = 0; k < 8; ++k)
      w2c[k] = *reinterpret_cast<const bf16x8*>(&w2s[k * 512 + lane8]);

    // issue W1 loads for NEXT slice (used next iteration)
    if (gs < 15) {
      const int gs2 = gs + 1;
      const int e2  = (gs2 >> 3) ? e1 : e0;
      const unsigned short* w1n = W1 + ((long)(e2 * 8 + (gs2 & 7)) << 12);
#pragma unroll
      for (int k = 0; k < 8; ++k)
        n1[k] = *reinterpret_cast<const bf16x8*>(&w1n[k * 512 + lane8]);
    }

    // ---- GEMM1: 32 hidden ch (permuted rows), K = 128
    f32x4 aA[4], aB[4];
#pragma unroll
    for (int nt = 0; nt < 4; ++nt) {
      aA[nt] = (f32x4){0.f, 0.f, 0.f, 0.f};
      aB[nt] = (f32x4){0.f, 0.f, 0.f, 0.f};
    }
#pragma unroll
    for (int ks = 0; ks < 4; ++ks) {
#pragma unroll
      for (int nt = 0; nt < 4; ++nt) {
        const int px = nt * 16 + r16;
        const bf16x8 xf = *reinterpret_cast<const bf16x8*>(
            &xw[(px * 16 + ((ks * 4 + q + px) & 15)) * 8]);
        aA[nt] = __builtin_amdgcn_mfma_f32_16x16x32_bf16(w1c[ks * 2 + 0], xf, aA[nt], 0, 0, 0);
        aB[nt] = __builtin_amdgcn_mfma_f32_16x16x32_bf16(w1c[ks * 2 + 1], xf, aB[nt], 0, 0, 0);
      }
    }

    // ---- bias + SiLU + gate -> GEMM2 B-fragments (true ch = base + q*8 + j)
    const float* b1e = b1 + e * CHID + grp * 32;
    const f32x4 bA = *reinterpret_cast<const f32x4*>(&b1e[q * 8]);
    const f32x4 bB = *reinterpret_cast<const f32x4*>(&b1e[q * 8 + 4]);
    union { bf16x8 v; unsigned int u[4]; } h[4];
#pragma unroll
    for (int nt = 0; nt < 4; ++nt) {
      h[nt].u[0] = silu_gate_pk(aA[nt][0] + bA[0], aA[nt][1] + bA[1], g);
      h[nt].u[1] = silu_gate_pk(aA[nt][2] + bA[2], aA[nt][3] + bA[3], g);
      h[nt].u[2] = silu_gate_pk(aB[nt][0] + bB[0], aB[nt][1] + bB[1], g);
      h[nt].u[3] = silu_gate_pk(aB[nt][2] + bB[2], aB[nt][3] + bB[3], g);
    }

    // ---- GEMM2 partial-K (this 32-ch chunk), weights from w2c registers
#pragma unroll
    for (int mt = 0; mt < 8; ++mt) {
#pragma unroll
      for (int nt = 0; nt < 4; ++nt)
        accO[mt][nt] = __builtin_amdgcn_mfma_f32_16x16x32_bf16(w2c[mt], h[nt].v, accO[mt][nt], 0, 0, 0);
    }
  }

  // ---- epilogue: per-wave LDS transpose (reuse dead x region; DS FIFO
  //      ordering within a wave -> no barriers), coalesced 16 B stores
  //      covering full 256 B lines per out row segment.
  float* eb = reinterpret_cast<float*>(xw);  // [16][68] f32 = 4352 B <= 16 KB
  const float* b2e0 = b2 + e0 * COUT;
  const float* b2e1 = b2 + e1 * COUT;
  const int  coR   = lane >> 2;              // 0..15
  const int  qtr   = lane & 3;
  const long orow0 = (long)b * COUT * HWPX + px0 + qtr * 16;
#pragma unroll
  for (int mt = 0; mt < 8; ++mt) {
    const int coW = q * 4;
    const f32x4 bias = g0 * (*reinterpret_cast<const f32x4*>(&b2e0[mt * 16 + coW])) +
                       g1 * (*reinterpret_cast<const f32x4*>(&b2e1[mt * 16 + coW]));
#pragma unroll
    for (int nt = 0; nt < 4; ++nt) {
      const f32x4 v = accO[mt][nt] + bias;
#pragma unroll
      for (int rr = 0; rr < 4; ++rr)
        eb[(coW + rr) * 68 + nt * 16 + r16] = v[rr];
    }
    {
      const long orow = orow0 + (long)(mt * 16 + coR) * HWPX;
#pragma unroll
      for (int i4 = 0; i4 < 4; ++i4) {
        const float4 ov = *reinterpret_cast<const float4*>(
            &eb[coR * 68 + qtr * 16 + i4 * 4]);
        *reinterpret_cast<float4*>(&out[orow + i4 * 4]) = ov;
      }
    }
  }
}

extern "C" void kernel_launch(void* const* d_in, const int* in_sizes, int n_in,
                              void* d_out, int out_size, void* d_ws, size_t ws_size,
                              hipStream_t stream) {
  const float* x   = (const float*)d_in[0];
  const float* wts = (const float*)d_in[1];
  const int*   idx = (const int*)d_in[2];
  const float* W1  = (const float*)d_in[3];
  const float* b1  = (const float*)d_in[4];
  const float* W2  = (const float*)d_in[5];
  const float* b2  = (const float*)d_in[6];
  float* out = (float*)d_out;

  unsigned short* W1c = (unsigned short*)d_ws;                    // 8*8*512*8
  unsigned short* W2c = (unsigned short*)d_ws + (8 * CHID * CIN); // same size

  convert_w_kernel<<<262144 / 256, 256, 0, stream>>>(W1, W2, W1c, W2c);
  moe_kernel<<<128 * 7, 256, 0, stream>>>(x, wts, idx, W1c, b1, W2c, b2, out);
}

// Round 6
// 316.371 us; speedup vs baseline: 1.5011x; 1.5011x over previous
//
#include <hip/hip_runtime.h>

// B=128, C_IN=128, C_HID=256, C_OUT=128, H*W=1600, E=8, TOP_K=2.
#define CIN   128
#define CHID  256
#define COUT  128
#define HWPX  1600
#define TPX   32          // pixels per tile
#define XOFF  0           // LDS: x tiles [0, 13*4096) shorts
#define WOFF  53248       // LDS: weight dbuf [53248, 53248+2*8192) shorts

typedef __attribute__((ext_vector_type(8))) short bf16x8;  // 8 bf16 = 4 VGPRs
typedef __attribute__((ext_vector_type(4))) float f32x4;   // MFMA C/D

__device__ __forceinline__ unsigned short f2bf(float f) {
  unsigned int u = __builtin_bit_cast(unsigned int, f);
  u += 0x7FFFu + ((u >> 16) & 1u);
  return (unsigned short)(u >> 16);
}
__device__ __forceinline__ unsigned int pack_bf2(float a, float b) {
  return (unsigned int)f2bf(a) | ((unsigned int)f2bf(b) << 16);
}
// Fast SiLU: v_exp_f32 + v_rcp_f32 (~1e-7 rel err, invisible under bf16).
__device__ __forceinline__ unsigned int silu_gate_pk(float a, float b, float g) {
  const float ea = __builtin_amdgcn_exp2f(a * -1.442695041f);
  const float eb = __builtin_amdgcn_exp2f(b * -1.442695041f);
  const float sa = g * a * __builtin_amdgcn_rcpf(1.0f + ea);
  const float sb = g * b * __builtin_amdgcn_rcpf(1.0f + eb);
  return pack_bf2(sa, sb);
}

// fp32->bf16 convert into LDS-slice-ordered, swizzled layouts (VERIFIED r1).
// W1b: [e][grp][512 chunks][8], chunk pos p = r*16 + ((c + r) & 15):
//   r = row-position in 32-row slice (h-trick: pos mt*16+row holds true
//   ch = (row>>2)*8 + (row&3) + mt*4), c = cin chunk (8 cin each).
// W2b: [e][grp][512 chunks][8], chunk pos p = co*4 + ((c + co + (co>>2)) & 3).
__global__ __launch_bounds__(256) void convert_w_kernel(
    const float* __restrict__ W1, const float* __restrict__ W2,
    unsigned short* __restrict__ W1b, unsigned short* __restrict__ W2b) {
  const int i   = blockIdx.x * 256 + threadIdx.x;   // 0 .. 262143
  const int j   = i & 7;
  const int p   = (i >> 3) & 511;
  const int grp = (i >> 12) & 7;
  const int e   = i >> 15;
  {
    const int r   = p >> 4;
    const int c   = ((p & 15) - r) & 15;
    const int row = r & 15, mt = r >> 4;
    const int ch  = grp * 32 + ((row >> 2) << 3) + (row & 3) + (mt << 2);
    W1b[i] = f2bf(W1[(e * CHID + ch) * CIN + c * 8 + j]);
  }
  {
    const int co = p >> 2;
    const int c  = ((p & 3) - co - (co >> 2)) & 3;
    const int ch = grp * 32 + c * 8 + j;
    W2b[i] = f2bf(W2[(e * COUT + co) * CHID + ch]);
  }
}

// Async stage of one 16 KB weight slice (W1 8 KB + W2 8 KB) into LDS via
// global_load_lds: zero VGPR cost; each wave stages a 2 KB quarter of each.
__device__ __forceinline__ void stage_w(const unsigned short* W1b,
                                        const unsigned short* W2b,
                                        int e, int grp, unsigned short* wb,
                                        int wave, int lane) {
  const long s = ((long)(e * 8 + grp) << 12) + wave * 1024 + lane * 8;
#pragma unroll
  for (int k2 = 0; k2 < 2; ++k2) {
    __builtin_amdgcn_global_load_lds(
        (const __attribute__((address_space(1))) unsigned int*)(W1b + s + k2 * 512),
        (__attribute__((address_space(3))) unsigned int*)(wb + wave * 1024 + k2 * 512),
        16, 0, 0);
    __builtin_amdgcn_global_load_lds(
        (const __attribute__((address_space(1))) unsigned int*)(W2b + s + k2 * 512),
        (__attribute__((address_space(3))) unsigned int*)(wb + 4096 + wave * 1024 + k2 * 512),
        16, 0, 0);
  }
}

// ---------------------------------------------------------------------------
// moe v6: 1 block/CU, gs-outer / tile-inner.
// Block = (b, 12-13 adjacent 32-px tiles); x staged once (104 KB LDS);
// weights double-buffered 2x16 KB, staged async (global_load_lds) with
// counted vmcnt(4) + raw barriers (loads always in flight, never drained).
// Per gs: W fragments read once into VGPRs, reused by all 4 tiles.
// accO = [4 tiles][8 mt][2 nt] = 256 regs -> 1 wave/SIMD, no spill (<512).
// ---------------------------------------------------------------------------
__global__ __launch_bounds__(256, 1) void moe_kernel(
    const float* __restrict__ x, const float* __restrict__ wts,
    const int* __restrict__ idx, const unsigned short* __restrict__ W1b,
    const float* __restrict__ b1, const unsigned short* __restrict__ W2b,
    const float* __restrict__ b2, float* __restrict__ out) {
  __shared__ __align__(16) unsigned short lds[69632];   // 136 KB

  const int tid  = threadIdx.x;
  const int wave = tid >> 6;
  const int lane = tid & 63;
  const int q    = lane >> 4;
  const int r16  = lane & 15;

  const int b    = blockIdx.x >> 2;
  const int blkp = blockIdx.x & 3;
  const int cnt  = (blkp < 2) ? 13 : 12;               // tiles in this block
  const int T0   = blkp * 12 + (blkp < 2 ? blkp : 2);  // first global tile
  const int ntw  = 3 + ((cnt == 13 && wave == 0) ? 1 : 0);
  const int ws   = 3 * wave + ((cnt == 13 && wave > 0) ? 1 : 0);

  const int   e0 = __builtin_amdgcn_readfirstlane(idx[b * 2 + 0]);
  const int   e1 = __builtin_amdgcn_readfirstlane(idx[b * 2 + 1]);
  const float g0 = wts[b * 2 + 0], g1 = wts[b * 2 + 1];

  // ---- issue async weight stages for slices 0 and 1 (land under x staging)
  stage_w(W1b, W2b, e0, 0, &lds[WOFF + 0 * 8192], wave, lane);
  stage_w(W1b, W2b, e0, 1, &lds[WOFF + 1 * 8192], wave, lane);

  // ---- stage this wave's x tiles (fp32 -> bf16, rotated LDS image; the
  //      trailing packs force vmcnt low, so W stages 0/1 also land before
  //      any wave reaches the first barrier).
  {
    const int p = lane & 31, hh = lane >> 5;
    for (int lt = ws; lt < ws + ntw; ++lt) {
      const int gt = T0 + lt;
      const float* xr = x + (long)b * CIN * HWPX + gt * TPX + p;
      unsigned short* xw = &lds[XOFF + lt * 4096];
#pragma unroll
      for (int it = 0; it < 8; ++it) {
        const int cc = it * 2 + hh;                    // cin chunk 0..15
        float v[8];
#pragma unroll
        for (int jj = 0; jj < 8; ++jj) v[jj] = xr[(long)(cc * 8 + jj) * HWPX];
        union { bf16x8 w; unsigned int u[4]; } t;
#pragma unroll
        for (int d = 0; d < 4; ++d) t.u[d] = pack_bf2(v[2 * d], v[2 * d + 1]);
        const int slot = (cc + p) & 15;                // rotation (bank spread)
        *reinterpret_cast<bf16x8*>(&xw[(p * 16 + slot) * 8]) = t.w;
      }
    }
  }

  f32x4 accO[4][8][2];
#pragma unroll
  for (int t = 0; t < 4; ++t)
#pragma unroll
    for (int mt = 0; mt < 8; ++mt)
#pragma unroll
      for (int nt = 0; nt < 2; ++nt) accO[t][mt][nt] = (f32x4){0.f, 0.f, 0.f, 0.f};

  for (int gs = 0; gs < 16; ++gs) {
    const int   sl  = gs >> 3;
    const int   grp = gs & 7;
    const int   e   = sl ? e1 : e0;
    const float g   = sl ? g1 : g0;
    unsigned short* wb = &lds[WOFF + (gs & 1) * 8192];

    // gate: my stage(gs) done (stage(gs+1)'s 4 loads may still fly), then
    // barrier => ALL waves' stage(gs) landed. Raw barrier: no vmcnt(0) drain.
    asm volatile("s_waitcnt vmcnt(4)" ::: "memory");
    __builtin_amdgcn_sched_barrier(0);
    __builtin_amdgcn_s_barrier();

    // ---- hoist this slice's fragments into VGPRs (shared by all tiles)
    bf16x8 w1f[8];
#pragma unroll
    for (int ks = 0; ks < 4; ++ks) {
      const int slotw = (ks * 4 + q + r16) & 15;       // same rotation both rows
      w1f[ks * 2 + 0] = *reinterpret_cast<const bf16x8*>(&wb[(r16 * 16 + slotw) * 8]);
      w1f[ks * 2 + 1] = *reinterpret_cast<const bf16x8*>(&wb[((r16 + 16) * 16 + slotw) * 8]);
    }
    bf16x8 w2f[8];
#pragma unroll
    for (int mt = 0; mt < 8; ++mt) {
      const int co = mt * 16 + r16;
      w2f[mt] = *reinterpret_cast<const bf16x8*>(
          &wb[4096 + (co * 4 + ((q + co + (co >> 2)) & 3)) * 8]);
    }
    const float* b1e = b1 + e * CHID + grp * 32;
    const f32x4 bA = *reinterpret_cast<const f32x4*>(&b1e[q * 8]);
    const f32x4 bB = *reinterpret_cast<const f32x4*>(&b1e[q * 8 + 4]);

    // ---- 3-4 tiles through this weight slice
#pragma unroll
    for (int t = 0; t < 4; ++t) {
      if (t < ntw) {
        const unsigned short* xw = &lds[XOFF + (ws + t) * 4096];
        f32x4 aA[2], aB[2];
#pragma unroll
        for (int nt = 0; nt < 2; ++nt) {
          aA[nt] = (f32x4){0.f, 0.f, 0.f, 0.f};
          aB[nt] = (f32x4){0.f, 0.f, 0.f, 0.f};
        }
#pragma unroll
        for (int ks = 0; ks < 4; ++ks) {
#pragma unroll
          for (int nt = 0; nt < 2; ++nt) {
            const int px = nt * 16 + r16;
            const bf16x8 xf = *reinterpret_cast<const bf16x8*>(
                &xw[(px * 16 + ((ks * 4 + q + px) & 15)) * 8]);
            aA[nt] = __builtin_amdgcn_mfma_f32_16x16x32_bf16(w1f[ks * 2 + 0], xf, aA[nt], 0, 0, 0);
            aB[nt] = __builtin_amdgcn_mfma_f32_16x16x32_bf16(w1f[ks * 2 + 1], xf, aB[nt], 0, 0, 0);
          }
        }
        union { bf16x8 v; unsigned int u[4]; } h[2];
#pragma unroll
        for (int nt = 0; nt < 2; ++nt) {
          h[nt].u[0] = silu_gate_pk(aA[nt][0] + bA[0], aA[nt][1] + bA[1], g);
          h[nt].u[1] = silu_gate_pk(aA[nt][2] + bA[2], aA[nt][3] + bA[3], g);
          h[nt].u[2] = silu_gate_pk(aB[nt][0] + bB[0], aB[nt][1] + bB[1], g);
          h[nt].u[3] = silu_gate_pk(aB[nt][2] + bB[2], aB[nt][3] + bB[3], g);
        }
#pragma unroll
        for (int mt = 0; mt < 8; ++mt)
#pragma unroll
          for (int nt = 0; nt < 2; ++nt)
            accO[t][mt][nt] = __builtin_amdgcn_mfma_f32_16x16x32_bf16(w2f[mt], h[nt].v, accO[t][mt][nt], 0, 0, 0);
      }
    }

    // all waves done reading wb (frag ds_reads completed before their MFMA
    // consumers above) -> safe to overwrite this buffer with slice gs+2.
    __builtin_amdgcn_s_barrier();
    if (gs <= 14) {
      const int gs2  = (gs + 2 <= 15) ? gs + 2 : 15;   // gs=14 re-stages 15
      const int e2   = (gs2 >> 3) ? e1 : e0;           // (dup keeps vmcnt gate exact)
      stage_w(W1b, W2b, e2, gs2 & 7, wb, wave, lane);
    }
  }

  // ---- epilogue: per-tile LDS transpose in the (dead) x region, then
  //      coalesced float4 stores. Wave-private regions, no barriers.
  const float* b2e0 = b2 + e0 * COUT;
  const float* b2e1 = b2 + e1 * COUT;
  const int coR = lane >> 2;
  const int qtr = lane & 3;
#pragma unroll
  for (int t = 0; t < 4; ++t) {
    if (t < ntw) {
      float* eb = reinterpret_cast<float*>(&lds[XOFF + (ws + t) * 4096]);
      const long px0   = (long)(T0 + ws + t) * TPX;
      const long obase = (long)b * COUT * HWPX + px0;
#pragma unroll
      for (int mt = 0; mt < 8; ++mt) {
        const int coW = q * 4;
        const f32x4 bias = g0 * (*reinterpret_cast<const f32x4*>(&b2e0[mt * 16 + coW])) +
                           g1 * (*reinterpret_cast<const f32x4*>(&b2e1[mt * 16 + coW]));
#pragma unroll
        for (int nt = 0; nt < 2; ++nt) {
          const f32x4 v = accO[t][mt][nt] + bias;
#pragma unroll
          for (int rr = 0; rr < 4; ++rr)
            eb[(coW + rr) * 36 + nt * 16 + r16] = v[rr];
        }
        const long orow = obase + (long)(mt * 16 + coR) * HWPX;
#pragma unroll
        for (int k = 0; k < 2; ++k) {
          const float4 ov = *reinterpret_cast<const float4*>(
              &eb[coR * 36 + k * 16 + qtr * 4]);
          *reinterpret_cast<float4*>(&out[orow + k * 16 + qtr * 4]) = ov;
        }
      }
    }
  }
}

extern "C" void kernel_launch(void* const* d_in, const int* in_sizes, int n_in,
                              void* d_out, int out_size, void* d_ws, size_t ws_size,
                              hipStream_t stream) {
  const float* x   = (const float*)d_in[0];
  const float* wts = (const float*)d_in[1];
  const int*   idx = (const int*)d_in[2];
  const float* W1  = (const float*)d_in[3];
  const float* b1  = (const float*)d_in[4];
  const float* W2  = (const float*)d_in[5];
  const float* b2  = (const float*)d_in[6];
  float* out = (float*)d_out;

  unsigned short* W1b = (unsigned short*)d_ws;                    // 8*8*512*8
  unsigned short* W2b = (unsigned short*)d_ws + (8 * CHID * CIN); // same size

  convert_w_kernel<<<262144 / 256, 256, 0, stream>>>(W1, W2, W1b, W2b);
  moe_kernel<<<128 * 4, 256, 0, stream>>>(x, wts, idx, W1b, b1, W2b, b2, out);
}

// Round 7
// 314.687 us; speedup vs baseline: 1.5091x; 1.0054x over previous
//
#include <hip/hip_runtime.h>

// B=128, C_IN=128, C_HID=256, C_OUT=128, H*W=1600, E=8, TOP_K=2.
#define CIN   128
#define CHID  256
#define COUT  128
#define HWPX  1600
#define TPX   32

typedef __attribute__((ext_vector_type(8))) short bf16x8;  // 8 bf16 = 4 VGPRs
typedef __attribute__((ext_vector_type(4))) float f32x4;   // MFMA C/D

__device__ __forceinline__ unsigned short f2bf(float f) {
  unsigned int u = __builtin_bit_cast(unsigned int, f);
  u += 0x7FFFu + ((u >> 16) & 1u);
  return (unsigned short)(u >> 16);
}
__device__ __forceinline__ unsigned int pack_bf2(float a, float b) {
  return (unsigned int)f2bf(a) | ((unsigned int)f2bf(b) << 16);
}
// Fast SiLU: v_exp_f32 + v_rcp_f32 (~1e-7 rel err, invisible under bf16).
__device__ __forceinline__ unsigned int silu_gate_pk(float a, float b, float g) {
  const float ea = __builtin_amdgcn_exp2f(a * -1.442695041f);
  const float eb = __builtin_amdgcn_exp2f(b * -1.442695041f);
  const float sa = g * a * __builtin_amdgcn_rcpf(1.0f + ea);
  const float sb = g * b * __builtin_amdgcn_rcpf(1.0f + eb);
  return pack_bf2(sa, sb);
}

// fp32->bf16 convert into PER-INSTRUCTION-ORDER fragment layout (verified r2):
// W1c: ((e*8+grp)*8 + ks*2 + half)*64 + lane; row ch = grp*32 +
//      ((r16>>2)<<3)+(r16&3)+(half<<2) (h-trick permuted), cin chunk = ks*4+q.
// W2c: ((e*8+grp)*8 + mt)*64 + lane; row co = mt*16+r16, ch = grp*32+q*8+j.
__global__ __launch_bounds__(256) void convert_w_kernel(
    const float* __restrict__ W1, const float* __restrict__ W2,
    unsigned short* __restrict__ W1c, unsigned short* __restrict__ W2c) {
  const int i    = blockIdx.x * 256 + threadIdx.x;   // 0 .. 262143
  const int j    = i & 7;
  const int lane = (i >> 3) & 63;
  const int r16  = lane & 15;
  const int q    = lane >> 4;
  {
    const int half = (i >> 9) & 1;
    const int ks   = (i >> 10) & 3;
    const int grp  = (i >> 12) & 7;
    const int e    = i >> 15;
    const int ch   = grp * 32 + ((r16 >> 2) << 3) + (r16 & 3) + (half << 2);
    const int c    = ks * 4 + q;
    W1c[i] = f2bf(W1[(e * CHID + ch) * CIN + c * 8 + j]);
  }
  {
    const int mt  = (i >> 9) & 7;
    const int grp = (i >> 12) & 7;
    const int e   = i >> 15;
    const int co  = mt * 16 + r16;
    W2c[i] = f2bf(W2[(e * COUT + co) * CHID + grp * 32 + q * 8 + j]);
  }
}

// ---------------------------------------------------------------------------
// moe v7 = verified v2 dataflow with HALF the per-wave footprint to double
// occupancy: 32-px tiles (nt=2), accO[8][2]=64 VGPR, 8 KB x-LDS per wave.
// Barrier-free independent waves; weights loaded from L1/L2 at point of use.
// __launch_bounds__(256,4): 128-VGPR cap -> 4 waves/SIMD, 16 waves/CU.
// ---------------------------------------------------------------------------
__global__ __launch_bounds__(256, 4) void moe_kernel(
    const float* __restrict__ x, const float* __restrict__ wts,
    const int* __restrict__ idx, const unsigned short* __restrict__ W1,
    const float* __restrict__ b1, const unsigned short* __restrict__ W2,
    const float* __restrict__ b2, float* __restrict__ out) {
  // LDS: 4 waves x 8 KB x-tile = 32 KB/block.
  __shared__ __align__(16) unsigned short lds[16384];

  const int tid  = threadIdx.x;
  const int wave = tid >> 6;
  const int lane = tid & 63;
  const int q    = lane >> 4;
  const int r16  = lane & 15;

  const int  b    = blockIdx.x / 13;
  const int  t13  = blockIdx.x % 13;
  const int  tile = t13 * 4 + wave;          // 0..51 (50,51 idle)
  if (tile >= 50) return;                    // no barriers anywhere -> safe

  unsigned short* xw = &lds[wave * 4096];    // this wave's 8 KB x region
  const int lane8 = lane * 8;

  const int   e0 = __builtin_amdgcn_readfirstlane(idx[b * 2 + 0]);
  const int   e1 = __builtin_amdgcn_readfirstlane(idx[b * 2 + 1]);
  const float g0 = wts[b * 2 + 0], g1 = wts[b * 2 + 1];

  // ---- stage x tile (within-wave producer/consumer -> no barrier needed)
  //      32 px: lanes 0..31 cover pixels, lane>>5 splits channel chunks.
  {
    const int p = lane & 31, hh = lane >> 5;
    const float* xr = x + (long)b * CIN * HWPX + tile * TPX + p;
#pragma unroll
    for (int it = 0; it < 8; ++it) {
      const int cc = it * 2 + hh;            // cin chunk 0..15
      float v[8];
#pragma unroll
      for (int jj = 0; jj < 8; ++jj) v[jj] = xr[(long)(cc * 8 + jj) * HWPX];
      union { bf16x8 w; unsigned int u[4]; } t;
#pragma unroll
      for (int d = 0; d < 4; ++d) t.u[d] = pack_bf2(v[2 * d], v[2 * d + 1]);
      const int slot = (cc + p) & 15;        // rotation swizzle (bank spread)
      *reinterpret_cast<bf16x8*>(&xw[(p * 16 + slot) * 8]) = t.w;
    }
  }

  f32x4 accO[8][2];
#pragma unroll
  for (int mt = 0; mt < 8; ++mt)
#pragma unroll
    for (int nt = 0; nt < 2; ++nt) accO[mt][nt] = (f32x4){0.f, 0.f, 0.f, 0.f};

  for (int gs = 0; gs < 16; ++gs) {
    const int   sl  = gs >> 3;
    const int   grp = gs & 7;
    const int   e   = sl ? e1 : e0;
    const float g   = sl ? g1 : g0;
    const unsigned short* w1s = W1 + ((long)(e * 8 + grp) << 12);
    const unsigned short* w2s = W2 + ((long)(e * 8 + grp) << 12);

    // ---- GEMM1: 32 hidden ch (permuted rows), K = 128
    f32x4 aA[2], aB[2];
#pragma unroll
    for (int nt = 0; nt < 2; ++nt) {
      aA[nt] = (f32x4){0.f, 0.f, 0.f, 0.f};
      aB[nt] = (f32x4){0.f, 0.f, 0.f, 0.f};
    }
#pragma unroll
    for (int ks = 0; ks < 4; ++ks) {
      const bf16x8 w0 = *reinterpret_cast<const bf16x8*>(
          &w1s[(ks * 2 + 0) * 512 + lane8]);
      const bf16x8 w1v = *reinterpret_cast<const bf16x8*>(
          &w1s[(ks * 2 + 1) * 512 + lane8]);
#pragma unroll
      for (int nt = 0; nt < 2; ++nt) {
        const int px = nt * 16 + r16;
        const bf16x8 xf = *reinterpret_cast<const bf16x8*>(
            &xw[(px * 16 + ((ks * 4 + q + px) & 15)) * 8]);
        aA[nt] = __builtin_amdgcn_mfma_f32_16x16x32_bf16(w0, xf, aA[nt], 0, 0, 0);
        aB[nt] = __builtin_amdgcn_mfma_f32_16x16x32_bf16(w1v, xf, aB[nt], 0, 0, 0);
      }
    }

    // ---- bias + SiLU + gate -> GEMM2 B-fragments (true ch = base + q*8 + j)
    const float* b1e = b1 + e * CHID + grp * 32;
    const f32x4 bA = *reinterpret_cast<const f32x4*>(&b1e[q * 8]);
    const f32x4 bB = *reinterpret_cast<const f32x4*>(&b1e[q * 8 + 4]);
    union { bf16x8 v; unsigned int u[4]; } h[2];
#pragma unroll
    for (int nt = 0; nt < 2; ++nt) {
      h[nt].u[0] = silu_gate_pk(aA[nt][0] + bA[0], aA[nt][1] + bA[1], g);
      h[nt].u[1] = silu_gate_pk(aA[nt][2] + bA[2], aA[nt][3] + bA[3], g);
      h[nt].u[2] = silu_gate_pk(aB[nt][0] + bB[0], aB[nt][1] + bB[1], g);
      h[nt].u[3] = silu_gate_pk(aB[nt][2] + bB[2], aB[nt][3] + bB[3], g);
    }

    // ---- GEMM2 partial-K (this 32-ch chunk)
#pragma unroll
    for (int mt = 0; mt < 8; ++mt) {
      const bf16x8 w2v = *reinterpret_cast<const bf16x8*>(
          &w2s[mt * 512 + lane8]);
#pragma unroll
      for (int nt = 0; nt < 2; ++nt)
        accO[mt][nt] = __builtin_amdgcn_mfma_f32_16x16x32_bf16(w2v, h[nt].v, accO[mt][nt], 0, 0, 0);
    }
  }

  // ---- epilogue: per-wave LDS transpose in the dead x region (wave-internal
  //      DS FIFO -> no barriers), then coalesced float4 stores.
  float* eb = reinterpret_cast<float*>(xw);  // 16 rows x 36 f32 = 2304 B
  const float* b2e0 = b2 + e0 * COUT;
  const float* b2e1 = b2 + e1 * COUT;
  const int  coR   = lane >> 2;              // 0..15
  const int  qtr   = lane & 3;
  const long obase = (long)b * COUT * HWPX + (long)tile * TPX;
#pragma unroll
  for (int mt = 0; mt < 8; ++mt) {
    const int coW = q * 4;
    const f32x4 bias = g0 * (*reinterpret_cast<const f32x4*>(&b2e0[mt * 16 + coW])) +
                       g1 * (*reinterpret_cast<const f32x4*>(&b2e1[mt * 16 + coW]));
#pragma unroll
    for (int nt = 0; nt < 2; ++nt) {
      const f32x4 v = accO[mt][nt] + bias;
#pragma unroll
      for (int rr = 0; rr < 4; ++rr)
        eb[(coW + rr) * 36 + nt * 16 + r16] = v[rr];
    }
    {
      const long orow = obase + (long)(mt * 16 + coR) * HWPX;
#pragma unroll
      for (int k = 0; k < 2; ++k) {
        const float4 ov = *reinterpret_cast<const float4*>(
            &eb[coR * 36 + k * 16 + qtr * 4]);
        *reinterpret_cast<float4*>(&out[orow + k * 16 + qtr * 4]) = ov;
      }
    }
  }
}

extern "C" void kernel_launch(void* const* d_in, const int* in_sizes, int n_in,
                              void* d_out, int out_size, void* d_ws, size_t ws_size,
                              hipStream_t stream) {
  const float* x   = (const float*)d_in[0];
  const float* wts = (const float*)d_in[1];
  const int*   idx = (const int*)d_in[2];
  const float* W1  = (const float*)d_in[3];
  const float* b1  = (const float*)d_in[4];
  const float* W2  = (const float*)d_in[5];
  const float* b2  = (const float*)d_in[6];
  float* out = (float*)d_out;

  unsigned short* W1c = (unsigned short*)d_ws;                    // 8*8*512*8
  unsigned short* W2c = (unsigned short*)d_ws + (8 * CHID * CIN); // same size

  convert_w_kernel<<<262144 / 256, 256, 0, stream>>>(W1, W2, W1c, W2c);
  moe_kernel<<<128 * 13, 256, 0, stream>>>(x, wts, idx, W1c, b1, W2c, b2, out);
}